// Round 1
// baseline (222.329 us; speedup 1.0000x reference)
//
#include <hip/hip_runtime.h>
#include <math.h>

// Problem constants
#define Bn   4
#define Cc   64
#define Hh   128
#define Ww   128
#define Oo   64
#define HW   16384
#define CIN  128
#define KK   9
#define NPAR 27

// Workspace layout (float offsets)
#define WB2_OFF 0        // bf16 W2[32][1152] = 36864 shorts = 18432 float slots
#define WB_OFF  18432    // bf16 W [64][576]  = 36864 shorts = 18432 float slots
#define PAR_OFF 36864    // f32 par[B][27][HW]

typedef __attribute__((ext_vector_type(8))) short bf16x8;
typedef __attribute__((ext_vector_type(4))) float f32x4;
typedef __attribute__((ext_vector_type(2), aligned(4))) float f32x2u;  // 4B-aligned pair

__device__ __forceinline__ short f2bf(float f) {
    unsigned u = __builtin_bit_cast(unsigned, f);
    u += 0x7FFFu + ((u >> 16) & 1u);        // RNE
    return (short)(u >> 16);
}

// ---------------------------------------------------------------------------
// Prepass: bf16 weight copies. Flat layouts line up:
//   wb2[j][c*9+k]: rows 0-17 = w_off flat, 18-26 = w_mod flat, 27-31 = 0
//   wb [o][c*9+k]: = w_reg flat
// ---------------------------------------------------------------------------
__global__ void prep_weights(const float* __restrict__ w_off,
                             const float* __restrict__ w_mod,
                             const float* __restrict__ w_reg,
                             float* __restrict__ ws) {
    int i = blockIdx.x * 256 + threadIdx.x;
    short* wb2 = (short*)(ws + WB2_OFF);
    short* wb  = (short*)(ws + WB_OFF);
    if (i < 32 * 1152) {
        int j = i / 1152;
        float v = 0.f;
        if (j < 18)      v = w_off[i];
        else if (j < 27) v = w_mod[i - 18 * 1152];
        wb2[i] = f2bf(v);
    }
    if (i < 64 * 576) wb[i] = f2bf(w_reg[i]);
}

// ---------------------------------------------------------------------------
// conv_mfma: 3x3 conv 128->27(pad 32) via MFMA per 16x4-pixel tile.
// C[32][64] = W2[32][1152] x V[1152][64], K chunked 18x64.
// NOW 8 waves / 512 threads per block: grid is fixed at 1024 blocks
// (= 4 blocks/CU), so doubling waves/block takes the CU from 16 -> 32
// resident waves (was the latency-bound limiter: MfmaUtil 2.3%,
// VALUBusy 24%, Occupancy 39%). Wave w: n-tile = w>>1 (16 px),
// m-tile = w&1 (16 out ch); each wave stages 8 V elements per K-chunk.
// Epilogue unchanged per (j,pixel): fused bias+coords+sigmoid -> par.
// ---------------------------------------------------------------------------
#define VSTR 72   // V_T row stride in bf16 (64 + 8 pad -> 2-way banks, free)

__global__ __launch_bounds__(512, 8)
void conv_mfma(const float* __restrict__ x, const float* __restrict__ g,
               const float* __restrict__ ws_,
               const float* __restrict__ b_off, const float* __restrict__ b_mod,
               float* __restrict__ parw) {
    __shared__ __align__(16) short V[64 * VSTR];

    const int tid = threadIdx.x;
    const int l = tid & 63, lm = l & 15, quad = l >> 4;
    const int w = __builtin_amdgcn_readfirstlane(tid >> 6);   // wave id 0..7
    const int nt = w >> 1;                                    // n-tile (pixel group)
    const int mt = w & 1;                                     // m-tile (out-ch half)
    const int b = blockIdx.z;
    const int ho0 = blockIdx.y * 4, wo0 = blockIdx.x * 16;
    const int ho_l = ho0 + (l >> 4), wo_l = wo0 + lm;         // staging pixel l

    const short* wb2 = (const short*)(ws_ + WB2_OFF);

    f32x4 acc = {0.f, 0.f, 0.f, 0.f};

    for (int cc = 0; cc < 18; cc++) {
        __syncthreads();
        union { short s[8]; bf16x8 v; } u;
#pragma unroll
        for (int i = 0; i < 8; i++) {
            int kkg = cc * 64 + w * 8 + i;        // wave-uniform
            int c = (kkg * 7282) >> 16;           // kkg/9 exact for <5832
            int k = kkg - c * 9;
            int dy = k / 3, dx = k - dy * 3;
            const float* plane = (c < Cc) ? (x + ((size_t)(b * Cc + c) << 14))
                                          : (g + ((size_t)(b * Cc + c - Cc) << 14));
            int y = ho_l + dy - 1, xx = wo_l + dx - 1;
            bool ok = ((unsigned)y < 128u) && ((unsigned)xx < 128u);
            int cy = min(max(y, 0), 127), cx = min(max(xx, 0), 127);
            float val = plane[(cy << 7) + cx];
            u.s[i] = f2bf(ok ? val : 0.f);
        }
        *(bf16x8*)&V[l * VSTR + w * 8] = u.v;
        __syncthreads();
#pragma unroll
        for (int ks = 0; ks < 2; ks++) {
            bf16x8 bfr = *(const bf16x8*)&V[(nt * 16 + lm) * VSTR + ks * 32 + quad * 8];
            bf16x8 a = *(const bf16x8*)(wb2 + (mt * 16 + lm) * 1152 + cc * 64 + ks * 32 + quad * 8);
            acc = __builtin_amdgcn_mfma_f32_16x16x32_bf16(a, bfr, acc, 0, 0, 0);
        }
    }

    // Epilogue: D[row j][col lm] -> par channels, fused bias/coords/sigmoid
    const int ho = ho0 + nt, wo = wo0 + lm;
    const int pix = (ho << 7) + wo;
    float* par = parw + (size_t)b * NPAR * HW + pix;
#pragma unroll
    for (int reg = 0; reg < 4; reg++) {
        int j = mt * 16 + quad * 4 + reg;
        float v = acc[reg];
        if (j < 18) {
            int k = j >> 1;
            float vb = v + b_off[j];
            if (j & 1) par[(size_t)(9 + k) * HW] = vb + (float)(k - (k / 3) * 3 + wo - 1);
            else       par[(size_t)k * HW]       = vb + (float)(k / 3 + ho - 1);
        } else if (j < 27) {
            int k = j - 18;
            par[(size_t)(18 + k) * HW] = 2.f / (1.f + __expf(-(v + b_mod[k])));
        }
    }
}

// ---------------------------------------------------------------------------
// deform_mfma: C[64o][64px] = W[64][576] x V[576][64] per 16x4-px tile.
// Stage A: bilinear params; x-corner pairs folded into pre-transformed
// weights so phase 1 is 2 dwordx2 loads + 4 FMA per element.
// NOW 8 waves / 512 threads: wave w owns (o-tile = w>>1, n-half = w&1),
// acc shrinks 4->2 fragments, staging 16->8 elements/lane. Same grid
// (1024 blocks = 4/CU) -> 32 resident waves/CU for gather-latency hiding.
// ---------------------------------------------------------------------------
__global__ __launch_bounds__(512, 8)
void deform_mfma(const float* __restrict__ x, const float* __restrict__ ws_,
                 const float* __restrict__ par_base, float* __restrict__ out) {
    __shared__ int2   sIdx[576];
    __shared__ float4 sWt [576];
    __shared__ __align__(16) short V[64 * VSTR];

    const int tid = threadIdx.x;
    const int l = tid & 63;
    const int lm = l & 15, quad = l >> 4;
    const int w = __builtin_amdgcn_readfirstlane(tid >> 6);   // wave id 0..7
    const int ot = w >> 1;                                    // o-tile (16 rows)
    const int nh = w & 1;                                     // n-half (2 of 4 nb)
    const int b = blockIdx.z;

    const float* par = par_base + (size_t)b * NPAR * HW;
    const short* wb  = (const short*)(ws_ + WB_OFF);
    const float* xb  = x + ((size_t)(b * Cc) << 14);

    // Stage A: bilinear params for 9 taps x 64 pixels
    for (int s = tid; s < 576; s += 512) {
        int k = s >> 6;
        int sl = s & 63;
        int sho = blockIdx.y * 4 + (sl >> 4);
        int swo = blockIdx.x * 16 + (sl & 15);
        int spix = (sho << 7) + swo;
        float py = par[(size_t)k * HW + spix];
        float px = par[(size_t)(9 + k) * HW + spix];
        float m  = par[(size_t)(18 + k) * HW + spix];
        float fy = floorf(py), fx = floorf(px);
        int y0 = (int)fy, x0 = (int)fx;
        int y1 = y0 + 1;
        float wy1 = py - fy, wx1 = px - fx;
        float wy0 = 1.f - wy1, wx0 = 1.f - wx1;
        bool vy0 = (unsigned)y0 < 128u, vy1 = (unsigned)y1 < 128u;
        bool vx0 = (unsigned)x0 < 128u, vx1 = (unsigned)(x0 + 1) < 128u;
        int cy0 = min(max(y0, 0), 127), cy1 = min(max(y1, 0), 127);
        int bx2 = min(max(x0, 0), 126);
        bool sel_lo = (x0 < 0), sel_hi = (x0 > 126);
        float w00 = (vy0 && vx0) ? wy0 * wx0 * m : 0.f;
        float w01 = (vy0 && vx1) ? wy0 * wx1 * m : 0.f;
        float w10 = (vy1 && vx0) ? wy1 * wx0 * m : 0.f;
        float w11 = (vy1 && vx1) ? wy1 * wx1 * m : 0.f;
        // fold boundary handling into pair weights: wa->[bx2], wb->[bx2+1]
        float wa0 = sel_lo ? w01 : (sel_hi ? 0.f : w00);
        float wb0 = sel_hi ? w00 : (sel_lo ? 0.f : w01);
        float wa1 = sel_lo ? w11 : (sel_hi ? 0.f : w10);
        float wb1 = sel_hi ? w10 : (sel_lo ? 0.f : w11);
        sIdx[s] = make_int2((cy0 << 7) + bx2, (cy1 << 7) + bx2);
        sWt[s]  = make_float4(wa0, wb0, wa1, wb1);
    }

    f32x4 acc[2];
#pragma unroll
    for (int nbi = 0; nbi < 2; nbi++) acc[nbi] = (f32x4){0.f, 0.f, 0.f, 0.f};

    const int wrow = ot * 16 + lm;    // this wave's A row for lane

    for (int ch = 0; ch < 9; ch++) {
        __syncthreads();              // prev phase-2 reads done / stage A done
        union { short s[8]; bf16x8 v; } u;
#pragma unroll
        for (int i = 0; i < 8; i++) {
            int kkg = ch * 64 + w * 8 + i;             // wave-uniform
            int c = (kkg * 7282) >> 16;                // kkg/9
            int k = kkg - c * 9;
            int2   id = sIdx[(k << 6) + l];
            float4 wv = sWt [(k << 6) + l];
            const float* xq = xb + ((size_t)c << 14);  // scalar base
            f32x2u p0 = *(const f32x2u*)(xq + id.x);
            f32x2u p1 = *(const f32x2u*)(xq + id.y);
            u.s[i] = f2bf(wv.x * p0.x + wv.y * p0.y + wv.z * p1.x + wv.w * p1.y);
        }
        *(bf16x8*)&V[l * VSTR + w * 8] = u.v;
        __syncthreads();
#pragma unroll
        for (int ks = 0; ks < 2; ks++) {
            bf16x8 a = *(const bf16x8*)(wb + wrow * 576 + ch * 64 + ks * 32 + quad * 8);
#pragma unroll
            for (int nbi = 0; nbi < 2; nbi++) {
                int nb = nh * 2 + nbi;
                bf16x8 bf = *(const bf16x8*)&V[(nb * 16 + lm) * VSTR + ks * 32 + quad * 8];
                acc[nbi] = __builtin_amdgcn_mfma_f32_16x16x32_bf16(a, bf, acc[nbi], 0, 0, 0);
            }
        }
    }

    const int wo = blockIdx.x * 16 + lm;
#pragma unroll
    for (int nbi = 0; nbi < 2; nbi++) {
        int nb = nh * 2 + nbi;
        int ho = blockIdx.y * 4 + nb;
        float* op = out + ((size_t)(b * Oo + ot * 16 + quad * 4) << 14) + (ho << 7) + wo;
#pragma unroll
        for (int reg = 0; reg < 4; reg++)
            op[(size_t)reg << 14] = acc[nbi][reg];
    }
}

// ---------------------------------------------------------------------------
extern "C" void kernel_launch(void* const* d_in, const int* in_sizes, int n_in,
                              void* d_out, int out_size, void* d_ws, size_t ws_size,
                              hipStream_t stream) {
    const float* x     = (const float*)d_in[0];
    const float* guide = (const float*)d_in[1];
    const float* w_off = (const float*)d_in[2];
    const float* b_off = (const float*)d_in[3];
    const float* w_mod = (const float*)d_in[4];
    const float* b_mod = (const float*)d_in[5];
    const float* w_reg = (const float*)d_in[6];
    float* out = (float*)d_out;
    float* ws  = (float*)d_ws;

    hipLaunchKernelGGL(prep_weights, dim3((32 * 1152 + 255) / 256), dim3(256),
                       0, stream, w_off, w_mod, w_reg, ws);
    hipLaunchKernelGGL(conv_mfma, dim3(Ww / 16, Hh / 4, Bn), dim3(512),
                       0, stream, x, guide, ws, b_off, b_mod, ws + PAR_OFF);
    hipLaunchKernelGGL(deform_mfma, dim3(Ww / 16, Hh / 4, Bn), dim3(512),
                       0, stream, x, ws, ws + PAR_OFF, out);
}